// Round 4
// baseline (320.313 us; speedup 1.0000x reference)
//
#include <hip/hip_runtime.h>

// GaLiTe attention layer, MI355X/gfx950 — all-fp32 implementation.
// Shapes: T=64 B=16 DIM=512 H=8 Dh=64 ETA=4 FD=256.
// All float tensors fp32 (R1's NaN under bf16-reading proves fp32 buffers);
// terminations int32.
// d_out = fp32 [ output(64*16*512) | kv_last(16*8*256*64) | nm_last(16*8*256) ].
//
// Precision note: attn_den is a 256-term cancellation sum reaching ~1e-3..1e-4
// vs term stdev ~3; the 2%-of-max threshold therefore requires fp32-grade
// projections. bf16 MFMA (rounds 2/3) decorrelates den -> garbage. So GEMMs
// run on the fp32 vector ALU (no fp32 MFMA on CDNA4).

#define T_N   64
#define B_N   16
#define DIM_N 512
#define H_N   8
#define DH_N  64
#define ETA_N 4
#define FD_N  256

#define OUT_ELEMS   524288   // T*B*DIM
#define KV_ELEMS    2097152  // B*H*FD*Dh

__device__ __forceinline__ float sigmoidf_(float x) {
    return 1.0f / (1.0f + __expf(-x));
}

// ---------------------------------------------------------------------------
// fp32 SGEMM: C[m][n] = sum_k A[m][k] * W[n][k] (+ bias[n])
// A: Mx512 row-major, W: Nx512 row-major, C: MxN row-major.
// Block 256 thr, 64x64 tile, BK=16, 4x4 microtile per thread.
// ---------------------------------------------------------------------------
__device__ __forceinline__ void gemm_f32_body(const float* __restrict__ A,
                                              const float* __restrict__ W,
                                              float* __restrict__ C, int N,
                                              const float* __restrict__ bias) {
    const int tid = threadIdx.x;
    const int mbase = blockIdx.x * 64;
    const int nbase = blockIdx.y * 64;
    if (nbase >= N) return;                 // small-N GEMMs: only y==0 active

    __shared__ float As[16][64];            // As[k][m]
    __shared__ float Bs[16][64];            // Bs[k][n]

    const int tx = tid & 15;                // n-quad
    const int ty = tid >> 4;                // m-quad
    const int sm = tid >> 2;                // staging row 0..63
    const int sk = (tid & 3) << 2;          // staging k offset 0,4,8,12
    const bool wok = (nbase + sm) < N;

    const float* Ap = A + (size_t)(mbase + sm) * 512 + sk;
    const float* Wp = W + (size_t)(nbase + sm) * 512 + sk;

    float acc[4][4];
    #pragma unroll
    for (int i = 0; i < 4; ++i)
        #pragma unroll
        for (int j = 0; j < 4; ++j) acc[i][j] = 0.f;

    for (int k0 = 0; k0 < 512; k0 += 16) {
        float4 av = *(const float4*)(Ap + k0);
        float4 wv = wok ? *(const float4*)(Wp + k0) : make_float4(0.f, 0.f, 0.f, 0.f);
        __syncthreads();                    // previous tile's readers done
        As[sk + 0][sm] = av.x; As[sk + 1][sm] = av.y;
        As[sk + 2][sm] = av.z; As[sk + 3][sm] = av.w;
        Bs[sk + 0][sm] = wv.x; Bs[sk + 1][sm] = wv.y;
        Bs[sk + 2][sm] = wv.z; Bs[sk + 3][sm] = wv.w;
        __syncthreads();
        #pragma unroll
        for (int k = 0; k < 16; ++k) {
            float4 a = *(const float4*)&As[k][ty << 2];
            float4 b = *(const float4*)&Bs[k][tx << 2];
            float ar[4] = {a.x, a.y, a.z, a.w};
            float br[4] = {b.x, b.y, b.z, b.w};
            #pragma unroll
            for (int i = 0; i < 4; ++i)
                #pragma unroll
                for (int j = 0; j < 4; ++j)
                    acc[i][j] = fmaf(ar[i], br[j], acc[i][j]);
        }
    }

    #pragma unroll
    for (int i = 0; i < 4; ++i) {
        const int m = mbase + (ty << 2) + i;
        #pragma unroll
        for (int j = 0; j < 4; ++j) {
            const int n = nbase + (tx << 2) + j;
            if (n < N) {
                float v = acc[i][j];
                if (bias) v += bias[n];
                C[(size_t)m * N + n] = v;
            }
        }
    }
}

struct ProjArgsF {
    const float* W[8];
    float*       D[8];
};

// z selects weight/dst. z<5: N=512 (q,k,v,beta,gamma); z>=5: N=32 (p1,p2,p3).
__global__ __launch_bounds__(256) void proj_kernel(const float* __restrict__ X, ProjArgsF a) {
    const int z = blockIdx.z;
    const int N = (z < 5) ? 512 : 32;
    gemm_f32_body(X, a.W[z], a.D[z], N, nullptr);
}

__global__ __launch_bounds__(256) void out_gemm_kernel(const float* __restrict__ A,
                                                       const float* __restrict__ W,
                                                       const float* __restrict__ bias,
                                                       float* __restrict__ C) {
    gemm_f32_body(A, W, C, 512, bias);
}

// ---------------------------------------------------------------------------
// Fused gating + sequential scan + attention readout (fp32 throughout).
// One block per (b,h): 256 threads = 4 waves. Wave w owns D-chunk [64w,64w+64),
// lane l owns d=l. kv[D][d]: 64 fp32 regs/thread (kvreg[i]=kv[w*64+i][l]).
// nm[D]: thread tid owns D=tid.
// attn output is written INTO the q buffer (qattn): each block reads exactly
// the cells (row=t*16+b, cols h*64..+63) it later overwrites in the same
// t-iteration, after two __syncthreads -> no hazard.
// ---------------------------------------------------------------------------
__global__ __launch_bounds__(256) void scan_kernel(
    float* qattn,
    const float* __restrict__ kb,  const float* __restrict__ vb,
    const float* __restrict__ bb,  const float* __restrict__ gb,
    const float* __restrict__ p1b, const float* __restrict__ p2b,
    const float* __restrict__ p3b, const int* __restrict__ term,
    const float* __restrict__ kv0, const float* __restrict__ nm0,
    float* __restrict__ dout) {
    const int bh = blockIdx.x;        // b*H + h
    const int b  = bh >> 3;
    const int h  = bh & 7;
    const int tid = threadIdx.x;
    const int w = tid >> 6;           // eta index e for this thread's D
    const int l = tid & 63;           // d (head-dim index)

    __shared__ float4 trip[256];      // (disc, gk, phiq, --) per D
    __shared__ float  gv_s[64];
    __shared__ float  numbuf[4][64];
    __shared__ float  denw[4];

    float kvreg[64];
    const size_t kvoff = ((size_t)bh * 256 + w * 64) * 64 + l;
    {
        const float* p = kv0 + kvoff;
        #pragma unroll
        for (int i = 0; i < 64; ++i) kvreg[i] = p[(size_t)i * 64];
    }
    float nm = nm0[(size_t)bh * 256 + tid];

    for (int t = 0; t < T_N; ++t) {
        const int row = t * B_N + b;
        const size_t base = (size_t)row * 512 + h * 64;
        const size_t pbase = (size_t)row * 32 + h * 4;

        // per-thread gating (D = tid = w*64 + l)
        float mask = 1.0f - (float)term[row];
        float p1v = p1b[pbase + w];
        float p2v = p2b[pbase + w];
        float p3v = p3b[pbase + w];
        float qv   = qattn[base + l];
        float kvv  = kb[base + l];
        float gpre = gb[base + l];
        float gf   = sigmoidf_(p3v) * sigmoidf_(gpre);   // gamma_feat[D]
        float phiq = fmaxf(p2v, 0.f) * qv;               // phi_q[D]
        float gk   = fmaxf(p1v, 0.f) * kvv * gf;         // gated_k[D]
        float disc = (1.0f - gf) * mask;                 // discount[D]
        nm = disc * nm + gk;                             // nm post-update
        float denp = phiq * nm;

        __syncthreads();   // previous iteration's trip/gv_s readers done
        trip[tid] = make_float4(disc, gk, phiq, 0.f);
        if (w == 0) {
            float vv   = vb[base + l];
            float bpre = bb[base + l];
            gv_s[l] = vv * sigmoidf_(bpre);              // gated_v[d]
        }
        __syncthreads();

        const float gvl = gv_s[l];
        const float4* tw = &trip[w * 64];
        float n0 = 0.f, n1 = 0.f, n2 = 0.f, n3 = 0.f;
        #pragma unroll
        for (int i = 0; i < 64; i += 4) {
            float4 t0 = tw[i + 0], t1 = tw[i + 1], t2 = tw[i + 2], t3 = tw[i + 3];
            kvreg[i + 0] = t0.x * kvreg[i + 0] + t0.y * gvl; n0 = fmaf(t0.z, kvreg[i + 0], n0);
            kvreg[i + 1] = t1.x * kvreg[i + 1] + t1.y * gvl; n1 = fmaf(t1.z, kvreg[i + 1], n1);
            kvreg[i + 2] = t2.x * kvreg[i + 2] + t2.y * gvl; n2 = fmaf(t2.z, kvreg[i + 2], n2);
            kvreg[i + 3] = t3.x * kvreg[i + 3] + t3.y * gvl; n3 = fmaf(t3.z, kvreg[i + 3], n3);
        }
        float num = (n0 + n1) + (n2 + n3);

        // attn_den: full 256-thread reduce = wave shuffle + cross-wave LDS
        float den = denp;
        #pragma unroll
        for (int ofs = 32; ofs > 0; ofs >>= 1) den += __shfl_xor(den, ofs);
        numbuf[w][l] = num;
        if (l == 0) denw[w] = den;
        __syncthreads();

        if (tid < 64) {
            float ntot = numbuf[0][tid] + numbuf[1][tid] + numbuf[2][tid] + numbuf[3][tid];
            float dtot = denw[0] + denw[1] + denw[2] + denw[3];
            qattn[base + tid] = ntot / (dtot + 1e-6f);   // attn overwrites q
        }
    }

    // final states -> d_out (fp32)
    {
        float* kp = dout + OUT_ELEMS + kvoff;
        #pragma unroll
        for (int i = 0; i < 64; ++i) kp[(size_t)i * 64] = kvreg[i];
        dout[OUT_ELEMS + KV_ELEMS + (size_t)bh * 256 + tid] = nm;
    }
}

// ---------------------------------------------------------------------------
extern "C" void kernel_launch(void* const* d_in, const int* in_sizes, int n_in,
                              void* d_out, int out_size, void* d_ws, size_t ws_size,
                              hipStream_t stream) {
    (void)in_sizes; (void)n_in; (void)out_size; (void)ws_size;

    const float* X    = (const float*)d_in[0];
    const int*   term = (const int*)  d_in[1];
    const float* kv0  = (const float*)d_in[2];
    const float* nm0  = (const float*)d_in[3];
    const float* Wq   = (const float*)d_in[4];
    const float* Wk   = (const float*)d_in[5];
    const float* Wv   = (const float*)d_in[6];
    const float* Wb   = (const float*)d_in[7];
    const float* Wg   = (const float*)d_in[8];
    const float* Wp1  = (const float*)d_in[9];
    const float* Wp2  = (const float*)d_in[10];
    const float* Wp3  = (const float*)d_in[11];
    const float* Wo   = (const float*)d_in[12];
    const float* bo   = (const float*)d_in[13];

    float* out = (float*)d_out;

    // ---- workspace (fp32, ~10.9 MB): q(=attn later),k,v,b,g + p1,p2,p3 ----
    float* qb  = (float*)d_ws;            // 1024x512, later holds attn
    float* kb  = qb  + 524288;
    float* vb  = kb  + 524288;
    float* bb  = vb  + 524288;
    float* gb  = bb  + 524288;
    float* p1b = gb  + 524288;            // 1024x32
    float* p2b = p1b + 32768;
    float* p3b = p2b + 32768;

    ProjArgsF pa;
    pa.W[0] = Wq;  pa.W[1] = Wk;  pa.W[2] = Wv;  pa.W[3] = Wb;
    pa.W[4] = Wg;  pa.W[5] = Wp1; pa.W[6] = Wp2; pa.W[7] = Wp3;
    pa.D[0] = qb;  pa.D[1] = kb;  pa.D[2] = vb;  pa.D[3] = bb;
    pa.D[4] = gb;  pa.D[5] = p1b; pa.D[6] = p2b; pa.D[7] = p3b;
    proj_kernel<<<dim3(16, 8, 8), 256, 0, stream>>>(X, pa);

    scan_kernel<<<128, 256, 0, stream>>>(qb, kb, vb, bb, gb, p1b, p2b, p3b,
                                         term, kv0, nm0, out);

    out_gemm_kernel<<<dim3(16, 8), 256, 0, stream>>>(qb, Wo, bo, out);
}

// Round 5
// 301.251 us; speedup vs baseline: 1.0633x; 1.0633x over previous
//
#include <hip/hip_runtime.h>

// GaLiTe attention layer, MI355X/gfx950 — all-fp32 (R4 proved fp32 projections
// are required: attn_den is a 256-term cancellation sum; bf16 decorrelates it).
// Shapes: T=64 B=16 DIM=512 H=8 Dh=64 ETA=4 FD=256.
// d_out = fp32 [ output(64*16*512) | kv_last(16*8*256*64) | nm_last(16*8*256) ].
//
// R5 structure:
//  - proj_kernel: ONE dispatch, 128x64-tile SGEMM, 8x4 microtile (z<5: N=512;
//    z>=5: N=32 guarded). 32 FMA per 3 ds_read_b128 per k -> issue-bound on VALU.
//  - scan_kernel: d-split x4 -> 512 blocks (2/CU), prefetched inputs, 2 barriers/t.
//  - out_gemm: same SGEMM body + bias.

#define T_N   64
#define B_N   16
#define DIM_N 512
#define H_N   8
#define DH_N  64
#define ETA_N 4
#define FD_N  256

#define OUT_ELEMS   524288   // T*B*DIM
#define KV_ELEMS    2097152  // B*H*FD*Dh

__device__ __forceinline__ float sigmoidf_(float x) {
    return 1.0f / (1.0f + __expf(-x));
}

// ---------------------------------------------------------------------------
// fp32 SGEMM body: C[m][n] = sum_k A[m][k]*W[n][k] (+bias), ldc=N.
// A: 1024x512 row-major, W: Nx512 row-major (N=512 or 32), K=512 fixed.
// Block 256 thr; tile 128(m) x 64(n); BK=16; 8x4 microtile/thread.
// LDS reads per k: As 2x b128 (4 distinct addrs/wave, broadcast) + Bs 1x b128
// (16 distinct, 2-way = free) -> VALU issue-bound (32 FMA = 64 cyc vs ~36 LDS).
// ---------------------------------------------------------------------------
__device__ __forceinline__ void gemm128x64(const float* __restrict__ A,
                                           const float* __restrict__ W,
                                           const float* __restrict__ bias,
                                           float* __restrict__ C, int N) {
    const int nbase = blockIdx.y * 64;
    if (nbase >= N) return;                 // N=32 GEMMs: only y==0 active

    __shared__ float As[16][128];           // [k][m]
    __shared__ float Bs[16][64];            // [k][n]

    const int tid = threadIdx.x;
    const int mbase = blockIdx.x * 128;
    const int tx = tid & 15;                // n-quad (n0 = nbase + tx*4)
    const int ty = tid >> 4;                // m-oct  (m0 = mbase + ty*8)
    const int ar = tid >> 1, ak = (tid & 1) * 8;   // A staging: row, k-offset
    const int br = tid >> 2, bk = (tid & 3) * 4;   // B staging
    const bool wok = (nbase + br) < N;

    const float* Ap = A + (size_t)(mbase + ar) * 512 + ak;
    const float* Wp = W + (size_t)(nbase + br) * 512 + bk;

    float acc[8][4];
    #pragma unroll
    for (int i = 0; i < 8; ++i)
        #pragma unroll
        for (int j = 0; j < 4; ++j) acc[i][j] = 0.f;

    for (int k0 = 0; k0 < 512; k0 += 16) {
        float4 a0 = *(const float4*)(Ap + k0);
        float4 a1 = *(const float4*)(Ap + k0 + 4);
        float4 bv = wok ? *(const float4*)(Wp + k0) : make_float4(0.f, 0.f, 0.f, 0.f);
        __syncthreads();                    // previous tile's readers done
        As[ak + 0][ar] = a0.x; As[ak + 1][ar] = a0.y;
        As[ak + 2][ar] = a0.z; As[ak + 3][ar] = a0.w;
        As[ak + 4][ar] = a1.x; As[ak + 5][ar] = a1.y;
        As[ak + 6][ar] = a1.z; As[ak + 7][ar] = a1.w;
        Bs[bk + 0][br] = bv.x; Bs[bk + 1][br] = bv.y;
        Bs[bk + 2][br] = bv.z; Bs[bk + 3][br] = bv.w;
        __syncthreads();
        #pragma unroll
        for (int k = 0; k < 16; ++k) {
            float4 x0 = *(const float4*)&As[k][ty * 8];
            float4 x1 = *(const float4*)&As[k][ty * 8 + 4];
            float4 yv = *(const float4*)&Bs[k][tx * 4];
            float xr[8] = {x0.x, x0.y, x0.z, x0.w, x1.x, x1.y, x1.z, x1.w};
            float yr[4] = {yv.x, yv.y, yv.z, yv.w};
            #pragma unroll
            for (int i = 0; i < 8; ++i)
                #pragma unroll
                for (int j = 0; j < 4; ++j)
                    acc[i][j] = fmaf(xr[i], yr[j], acc[i][j]);
        }
    }

    #pragma unroll
    for (int i = 0; i < 8; ++i) {
        const int m = mbase + ty * 8 + i;
        #pragma unroll
        for (int j = 0; j < 4; ++j) {
            const int n = nbase + tx * 4 + j;
            if (n < N) {
                float v = acc[i][j];
                if (bias) v += bias[n];
                C[(size_t)m * N + n] = v;
            }
        }
    }
}

struct ProjW {
    const float* W[8];
    float*       D[8];
};

// z<5: N=512 (q,k,v,beta,gamma); z>=5: N=32 (p1,p2,p3). grid (8,8,8).
__global__ __launch_bounds__(256) void proj_kernel(const float* __restrict__ X, ProjW a) {
    const int z = blockIdx.z;
    const int N = (z < 5) ? 512 : 32;
    gemm128x64(X, a.W[z], nullptr, a.D[z], N);
}

// grid (8,8): out[m][n] = attn @ Wo^T + bo
__global__ __launch_bounds__(256) void out_gemm_kernel(const float* __restrict__ A,
                                                       const float* __restrict__ W,
                                                       const float* __restrict__ bias,
                                                       float* __restrict__ C) {
    gemm128x64(A, W, bias, C, 512);
}

// ---------------------------------------------------------------------------
// Fused gating + sequential scan + attention readout, d-split x4.
// Grid 512: block = (bh, s); s owns d in [16s, 16s+16). 256 thr = 4 waves.
// Gating: thread tid owns D=tid (all 256 D per block; redundant across s).
// kv state: wave w, lane l: g=l>>4, dsub=l&15; kvreg[i] = kv[w*64+g*16+i][dbase+dsub].
// nm[D]: thread tid owns D=tid (redundant across s; s==0 writes it out).
// attn is written INTO the v buffer: block s reads v only at cols [16s,16s+16)
// of row t (prefetched at t-1, i.e. before the row-t attn write) -> no hazard,
// and out_gemm reads it after scan completes.
// ---------------------------------------------------------------------------
__global__ __launch_bounds__(256) void scan_kernel(
    const float* __restrict__ qb,  const float* __restrict__ kb,
    float* vb /* v in, attn out */, const float* __restrict__ bb,
    const float* __restrict__ gb,  const float* __restrict__ p1b,
    const float* __restrict__ p2b, const float* __restrict__ p3b,
    const int* __restrict__ term,
    const float* __restrict__ kv0, const float* __restrict__ nm0,
    float* __restrict__ dout) {
    const int blk = blockIdx.x;       // 512 = 128 bh x 4 splits
    const int bh = blk >> 2;
    const int s  = blk & 3;
    const int b  = bh >> 3;
    const int h  = bh & 7;
    const int dbase = s * 16;
    const int tid = threadIdx.x;
    const int w = tid >> 6;           // eta index e for D=tid
    const int l = tid & 63;
    const int g = l >> 4;             // D-subchunk within wave
    const int dsub = l & 15;
    const int dloc = dbase + dsub;    // this thread's d column

    __shared__ float4 trip[256];      // (disc, gk, phiq, --) per D
    __shared__ float  numbuf[4][16];
    __shared__ float  denw[4];

    // kv state: kvreg[i] = kv[w*64 + g*16 + i][dloc]
    float kvreg[16];
    const size_t kvoff = ((size_t)bh * 256 + w * 64 + g * 16) * 64 + dloc;
    #pragma unroll
    for (int i = 0; i < 16; ++i) kvreg[i] = kv0[kvoff + (size_t)i * 64];
    float nm = nm0[(size_t)bh * 256 + tid];

    // preload t=0 inputs
    float cq, ck, cg, cv, cbb, cp1, cp2, cp3, cmask;
    {
        const int row = b;
        const size_t base = (size_t)row * 512 + h * 64;
        const size_t pb = (size_t)row * 32 + h * 4;
        cq = qb[base + l]; ck = kb[base + l]; cg = gb[base + l];
        cv = vb[base + dloc]; cbb = bb[base + dloc];
        cp1 = p1b[pb + w]; cp2 = p2b[pb + w]; cp3 = p3b[pb + w];
        cmask = 1.0f - (float)term[row];
    }

    for (int t = 0; t < T_N; ++t) {
        const int row = t * B_N + b;
        const size_t base = (size_t)row * 512 + h * 64;

        // prefetch t+1 (issues early; s_waitcnt lands at the rotate)
        float nq = 0.f, nk = 0.f, ng = 0.f, nv = 0.f, nbv = 0.f;
        float np1 = 0.f, np2 = 0.f, np3 = 0.f, nmask = 0.f;
        if (t + 1 < T_N) {
            const int r2 = row + B_N;
            const size_t b2 = (size_t)r2 * 512 + h * 64;
            const size_t pb2 = (size_t)r2 * 32 + h * 4;
            nq = qb[b2 + l]; nk = kb[b2 + l]; ng = gb[b2 + l];
            nv = vb[b2 + dloc]; nbv = bb[b2 + dloc];
            np1 = p1b[pb2 + w]; np2 = p2b[pb2 + w]; np3 = p3b[pb2 + w];
            nmask = 1.0f - (float)term[r2];
        }

        // gating for D = tid
        float gf   = sigmoidf_(cp3) * sigmoidf_(cg);   // gamma_feat[D]
        float phiq = fmaxf(cp2, 0.f) * cq;             // phi_q[D]
        float gk   = fmaxf(cp1, 0.f) * ck * gf;        // gated_k[D]
        float disc = (1.0f - gf) * cmask;              // discount[D]
        nm = disc * nm + gk;                           // nm post-update
        float denp = phiq * nm;
        float gvl  = cv * sigmoidf_(cbb);              // gated_v[dloc]

        // barrier A: all trip readers of t-1 passed barrier B of t-1 already
        // (reads precede numbuf writes, which precede barrier B) -> writing
        // trip here only needs one barrier to publish.
        trip[tid] = make_float4(disc, gk, phiq, 0.f);
        __syncthreads();

        const float4* tw = &trip[w * 64 + g * 16];
        float n0 = 0.f, n1 = 0.f;
        #pragma unroll
        for (int i = 0; i < 16; i += 2) {
            float4 t0 = tw[i], t1 = tw[i + 1];
            kvreg[i]     = t0.x * kvreg[i]     + t0.y * gvl; n0 = fmaf(t0.z, kvreg[i],     n0);
            kvreg[i + 1] = t1.x * kvreg[i + 1] + t1.y * gvl; n1 = fmaf(t1.z, kvreg[i + 1], n1);
        }
        float num = n0 + n1;
        // combine the 4 g-groups (same d) within the wave
        num += __shfl_xor(num, 16);
        num += __shfl_xor(num, 32);

        // den: full 256-D reduce (wave shuffle + cross-wave LDS)
        float den = denp;
        #pragma unroll
        for (int ofs = 32; ofs > 0; ofs >>= 1) den += __shfl_xor(den, ofs);

        if (l < 16) numbuf[w][l] = num;
        if (l == 0) denw[w] = den;
        __syncthreads();                  // barrier B

        if (tid < 16) {
            float ntot = numbuf[0][tid] + numbuf[1][tid] + numbuf[2][tid] + numbuf[3][tid];
            float dtot = denw[0] + denw[1] + denw[2] + denw[3];
            vb[base + dbase + tid] = ntot / (dtot + 1e-6f);   // attn -> v buffer
        }

        cq = nq; ck = nk; cg = ng; cv = nv; cbb = nbv;
        cp1 = np1; cp2 = np2; cp3 = np3; cmask = nmask;
    }

    // final states -> d_out
    {
        float* kp = dout + OUT_ELEMS + kvoff;
        #pragma unroll
        for (int i = 0; i < 16; ++i) kp[(size_t)i * 64] = kvreg[i];
        if (s == 0)
            dout[OUT_ELEMS + KV_ELEMS + (size_t)bh * 256 + tid] = nm;
    }
}

// ---------------------------------------------------------------------------
extern "C" void kernel_launch(void* const* d_in, const int* in_sizes, int n_in,
                              void* d_out, int out_size, void* d_ws, size_t ws_size,
                              hipStream_t stream) {
    (void)in_sizes; (void)n_in; (void)out_size; (void)ws_size;

    const float* X    = (const float*)d_in[0];
    const int*   term = (const int*)  d_in[1];
    const float* kv0  = (const float*)d_in[2];
    const float* nm0  = (const float*)d_in[3];
    const float* Wq   = (const float*)d_in[4];
    const float* Wk   = (const float*)d_in[5];
    const float* Wv   = (const float*)d_in[6];
    const float* Wb   = (const float*)d_in[7];
    const float* Wg   = (const float*)d_in[8];
    const float* Wp1  = (const float*)d_in[9];
    const float* Wp2  = (const float*)d_in[10];
    const float* Wp3  = (const float*)d_in[11];
    const float* Wo   = (const float*)d_in[12];
    const float* bo   = (const float*)d_in[13];

    float* out = (float*)d_out;

    // ---- workspace (fp32, 10.9 MB — proven safe in R4) ----
    float* qb  = (float*)d_ws;            // 1024x512
    float* kb  = qb  + 524288;
    float* vb  = kb  + 524288;            // v, later attn
    float* bb  = vb  + 524288;
    float* gb  = bb  + 524288;
    float* p1b = gb  + 524288;            // 1024x32
    float* p2b = p1b + 32768;
    float* p3b = p2b + 32768;

    ProjW pa;
    pa.W[0] = Wq;  pa.W[1] = Wk;  pa.W[2] = Wv;  pa.W[3] = Wb;
    pa.W[4] = Wg;  pa.W[5] = Wp1; pa.W[6] = Wp2; pa.W[7] = Wp3;
    pa.D[0] = qb;  pa.D[1] = kb;  pa.D[2] = vb;  pa.D[3] = bb;
    pa.D[4] = gb;  pa.D[5] = p1b; pa.D[6] = p2b; pa.D[7] = p3b;
    proj_kernel<<<dim3(8, 8, 8), 256, 0, stream>>>(X, pa);

    scan_kernel<<<512, 256, 0, stream>>>(qb, kb, vb, bb, gb, p1b, p2b, p3b,
                                         term, kv0, nm0, out);

    out_gemm_kernel<<<dim3(8, 8), 256, 0, stream>>>(vb, Wo, bo, out);
}

// Round 7
// 259.090 us; speedup vs baseline: 1.2363x; 1.1627x over previous
//
#include <hip/hip_runtime.h>

// GaLiTe attention layer, MI355X/gfx950 — all-fp32 (fp32 projections required:
// attn_den is a 256-term cancellation sum; bf16 decorrelates it — R2/R3).
// Shapes: T=64 B=16 DIM=512 H=8 Dh=64 ETA=4 FD=256.
// d_out = fp32 [ output(64*16*512) | kv_last(16*8*256*64) | nm_last(16*8*256) ].
//
// R7 = R6 with the scan indexing bug fixed:
//   D = e*64 + d_inner; gating needs q/k/g at d_inner = D & 63.
//   Lane owns D0=4l -> d_inner0 = 4*(l&15), NOT 4l (R6 read other heads' cols).

#define T_N   64
#define B_N   16
#define DIM_N 512
#define H_N   8
#define DH_N  64
#define ETA_N 4
#define FD_N  256

#define OUT_ELEMS   524288   // T*B*DIM
#define KV_ELEMS    2097152  // B*H*FD*Dh

__device__ __forceinline__ float sigmoidf_(float x) {
    return 1.0f / (1.0f + __expf(-x));
}

// ---------------------------------------------------------------------------
// fp32 SGEMM: C[m][n] = sum_k A[m][k]*W[n][k] (+bias), ldc=N, K=512.
// Block 256 thr; tile 64(m) x 64(n); BK=16; 4x4 microtile/thread.
// Register-prefetch: next tile's global loads issue right after LDS publish.
// LDS stride 68: bank-conflict-free reads.
// ---------------------------------------------------------------------------
__device__ __forceinline__ void gemm64(const float* __restrict__ A,
                                       const float* __restrict__ W,
                                       const float* __restrict__ bias,
                                       float* __restrict__ C, int N) {
    const int nbase = blockIdx.y * 64;
    if (nbase >= N) return;                 // N=32 GEMMs: only y==0 active

    __shared__ float As[16][68];            // [k][m], padded
    __shared__ float Bs[16][68];            // [k][n], padded

    const int tid = threadIdx.x;
    const int mbase = blockIdx.x * 64;
    const int tx = tid & 15;                // n-quad
    const int ty = tid >> 4;                // m-quad
    const int sr = tid >> 2;                // staging row 0..63
    const int sk = (tid & 3) << 2;          // staging k 0,4,8,12
    const bool wok = (nbase + sr) < N;

    const float* Ap = A + (size_t)(mbase + sr) * 512 + sk;
    const float* Wp = W + (size_t)(nbase + sr) * 512 + sk;

    float4 av = *(const float4*)Ap;
    float4 wv = wok ? *(const float4*)Wp : make_float4(0.f, 0.f, 0.f, 0.f);

    float acc[4][4];
    #pragma unroll
    for (int i = 0; i < 4; ++i)
        #pragma unroll
        for (int j = 0; j < 4; ++j) acc[i][j] = 0.f;

    for (int k0 = 0; k0 < 512; k0 += 16) {
        __syncthreads();                    // previous tile's readers done
        As[sk + 0][sr] = av.x; As[sk + 1][sr] = av.y;
        As[sk + 2][sr] = av.z; As[sk + 3][sr] = av.w;
        Bs[sk + 0][sr] = wv.x; Bs[sk + 1][sr] = wv.y;
        Bs[sk + 2][sr] = wv.z; Bs[sk + 3][sr] = wv.w;
        __syncthreads();
        if (k0 + 16 < 512) {                // prefetch next tile during compute
            av = *(const float4*)(Ap + k0 + 16);
            wv = wok ? *(const float4*)(Wp + k0 + 16) : make_float4(0.f, 0.f, 0.f, 0.f);
        }
        #pragma unroll
        for (int k = 0; k < 16; ++k) {
            float4 a = *(const float4*)&As[k][ty << 2];
            float4 bq = *(const float4*)&Bs[k][tx << 2];
            float ar[4] = {a.x, a.y, a.z, a.w};
            float br[4] = {bq.x, bq.y, bq.z, bq.w};
            #pragma unroll
            for (int i = 0; i < 4; ++i)
                #pragma unroll
                for (int j = 0; j < 4; ++j)
                    acc[i][j] = fmaf(ar[i], br[j], acc[i][j]);
        }
    }

    #pragma unroll
    for (int i = 0; i < 4; ++i) {
        const int m = mbase + (ty << 2) + i;
        #pragma unroll
        for (int j = 0; j < 4; ++j) {
            const int n = nbase + (tx << 2) + j;
            if (n < N) {
                float v = acc[i][j];
                if (bias) v += bias[n];
                C[(size_t)m * N + n] = v;
            }
        }
    }
}

struct ProjW {
    const float* W[8];
    float*       D[8];
};

// z<5: N=512 (q,k,v,beta,gamma); z>=5: N=32 (p1,p2,p3). grid (16,8,8).
__global__ __launch_bounds__(256) void proj_kernel(const float* __restrict__ X, ProjW a) {
    const int z = blockIdx.z;
    const int N = (z < 5) ? 512 : 32;
    gemm64(X, a.W[z], nullptr, a.D[z], N);
}

// grid (16,8): out = attn @ Wo^T + bo
__global__ __launch_bounds__(256) void out_gemm_kernel(const float* __restrict__ A,
                                                       const float* __restrict__ W,
                                                       const float* __restrict__ bias,
                                                       float* __restrict__ C) {
    gemm64(A, W, bias, C, 512);
}

// ---------------------------------------------------------------------------
// Scan v3 (fixed): barrier-free, LDS-free.
// Grid 512: blk = bh*4 + s. Block 256 thr = 4 INDEPENDENT waves.
// Wave w covers d-cols dw = s*16 + w*4 .. +4.
// Lane l owns D in {4l..4l+4} x the wave's 4 d-cols: kv[4][4], nm[4].
//   D = e*64 + d_inner: e = l>>4, d_inner = 4*(l&15) + j.
// Gating loads q/k/g at d_inner (quarter-wave broadcast), p* at e.
// num[c], den: full-wave shfl_xor butterflies.
// attn overwrites the v buffer (wave reads v(row t+1) before writing attn(row t);
// each wave owns its 4 cols exclusively).
// ---------------------------------------------------------------------------
__global__ __launch_bounds__(256) void scan_kernel(
    const float* __restrict__ qb,  const float* __restrict__ kb,
    float* vb /* v in, attn out */, const float* __restrict__ bb,
    const float* __restrict__ gb,  const float* __restrict__ p1b,
    const float* __restrict__ p2b, const float* __restrict__ p3b,
    const int* __restrict__ term,
    const float* __restrict__ kv0, const float* __restrict__ nm0,
    float* __restrict__ dout) {
    const int blk = blockIdx.x;       // 512 = 128 bh x 4 splits
    const int bh = blk >> 2;
    const int s  = blk & 3;
    const int b  = bh >> 3;
    const int h  = bh & 7;
    const int tid = threadIdx.x;
    const int w = tid >> 6;
    const int l = tid & 63;
    const int dw  = s * 16 + w * 4;   // wave's 4 d-cols
    const int D0  = l << 2;           // lane's first D
    const int eta = l >> 4;           // e = D0/64
    const int di0 = (l & 15) << 2;    // d_inner0 = D0 & 63  (R6 bug: used D0)

    // state: kv[j][c] = kv[D0+j][dw+c], nm[j] = nm[D0+j]
    float kv[4][4];
    float nm[4];
    {
        const float* kp = kv0 + ((size_t)bh * 256 + D0) * 64 + dw;
        #pragma unroll
        for (int j = 0; j < 4; ++j) {
            float4 r = *(const float4*)(kp + (size_t)j * 64);
            kv[j][0] = r.x; kv[j][1] = r.y; kv[j][2] = r.z; kv[j][3] = r.w;
        }
        float4 n4 = *(const float4*)(nm0 + (size_t)bh * 256 + D0);
        nm[0] = n4.x; nm[1] = n4.y; nm[2] = n4.z; nm[3] = n4.w;
    }

    // preload t=0
    float4 cq, ck, cg, cv, cb;
    float cp1, cp2, cp3, cmask;
    {
        const size_t base = (size_t)b * 512 + h * 64;
        const size_t pb = (size_t)b * 32 + h * 4;
        cq = *(const float4*)(qb + base + di0);
        ck = *(const float4*)(kb + base + di0);
        cg = *(const float4*)(gb + base + di0);
        cv = *(const float4*)(vb + base + dw);
        cb = *(const float4*)(bb + base + dw);
        cp1 = p1b[pb + eta]; cp2 = p2b[pb + eta]; cp3 = p3b[pb + eta];
        cmask = 1.0f - (float)term[b];
    }

    for (int t = 0; t < T_N; ++t) {
        const int row = t * B_N + b;
        const size_t base = (size_t)row * 512 + h * 64;

        // prefetch t+1
        float4 nq = {}, nk = {}, ng = {}, nv = {}, nb4 = {};
        float np1 = 0.f, np2 = 0.f, np3 = 0.f, nmask = 0.f;
        if (t + 1 < T_N) {
            const int r2 = row + B_N;
            const size_t b2 = (size_t)r2 * 512 + h * 64;
            const size_t pb2 = (size_t)r2 * 32 + h * 4;
            nq = *(const float4*)(qb + b2 + di0);
            nk = *(const float4*)(kb + b2 + di0);
            ng = *(const float4*)(gb + b2 + di0);
            nv = *(const float4*)(vb + b2 + dw);
            nb4 = *(const float4*)(bb + b2 + dw);
            np1 = p1b[pb2 + eta]; np2 = p2b[pb2 + eta]; np3 = p3b[pb2 + eta];
            nmask = 1.0f - (float)term[r2];
        }

        // gated_v for the wave's 4 d-cols (redundant per lane, cheap)
        const float gv0 = cv.x * sigmoidf_(cb.x);
        const float gv1 = cv.y * sigmoidf_(cb.y);
        const float gv2 = cv.z * sigmoidf_(cb.z);
        const float gv3 = cv.w * sigmoidf_(cb.w);

        const float p1r = fmaxf(cp1, 0.f);
        const float p2r = fmaxf(cp2, 0.f);
        const float sp3 = sigmoidf_(cp3);

        const float qj[4] = {cq.x, cq.y, cq.z, cq.w};
        const float kj[4] = {ck.x, ck.y, ck.z, ck.w};
        const float gj[4] = {cg.x, cg.y, cg.z, cg.w};

        float denp = 0.f, n0 = 0.f, n1 = 0.f, n2 = 0.f, n3 = 0.f;
        #pragma unroll
        for (int j = 0; j < 4; ++j) {
            const float gf   = sp3 * sigmoidf_(gj[j]);
            const float phiq = p2r * qj[j];
            const float gk   = p1r * kj[j] * gf;
            const float disc = (1.0f - gf) * cmask;
            nm[j] = disc * nm[j] + gk;
            denp = fmaf(phiq, nm[j], denp);
            kv[j][0] = disc * kv[j][0] + gk * gv0; n0 = fmaf(phiq, kv[j][0], n0);
            kv[j][1] = disc * kv[j][1] + gk * gv1; n1 = fmaf(phiq, kv[j][1], n1);
            kv[j][2] = disc * kv[j][2] + gk * gv2; n2 = fmaf(phiq, kv[j][2], n2);
            kv[j][3] = disc * kv[j][3] + gk * gv3; n3 = fmaf(phiq, kv[j][3], n3);
        }

        // full-wave butterfly reductions (lane D-sets tile [0,256))
        #pragma unroll
        for (int ofs = 1; ofs < 64; ofs <<= 1) {
            n0   += __shfl_xor(n0, ofs);
            n1   += __shfl_xor(n1, ofs);
            n2   += __shfl_xor(n2, ofs);
            n3   += __shfl_xor(n3, ofs);
            denp += __shfl_xor(denp, ofs);
        }

        if (l < 4) {
            const float num = (l == 0) ? n0 : (l == 1) ? n1 : (l == 2) ? n2 : n3;
            vb[base + dw + l] = num / (denp + 1e-6f);   // attn -> v buffer
        }

        cq = nq; ck = nk; cg = ng; cv = nv; cb = nb4;
        cp1 = np1; cp2 = np2; cp3 = np3; cmask = nmask;
    }

    // final states -> d_out
    {
        float* kp = dout + OUT_ELEMS + ((size_t)bh * 256 + D0) * 64 + dw;
        #pragma unroll
        for (int j = 0; j < 4; ++j)
            *(float4*)(kp + (size_t)j * 64) = make_float4(kv[j][0], kv[j][1], kv[j][2], kv[j][3]);
        if (s == 0 && w == 0)
            *(float4*)(dout + OUT_ELEMS + KV_ELEMS + (size_t)bh * 256 + D0) =
                make_float4(nm[0], nm[1], nm[2], nm[3]);
    }
}

// ---------------------------------------------------------------------------
extern "C" void kernel_launch(void* const* d_in, const int* in_sizes, int n_in,
                              void* d_out, int out_size, void* d_ws, size_t ws_size,
                              hipStream_t stream) {
    (void)in_sizes; (void)n_in; (void)out_size; (void)ws_size;

    const float* X    = (const float*)d_in[0];
    const int*   term = (const int*)  d_in[1];
    const float* kv0  = (const float*)d_in[2];
    const float* nm0  = (const float*)d_in[3];
    const float* Wq   = (const float*)d_in[4];
    const float* Wk   = (const float*)d_in[5];
    const float* Wv   = (const float*)d_in[6];
    const float* Wb   = (const float*)d_in[7];
    const float* Wg   = (const float*)d_in[8];
    const float* Wp1  = (const float*)d_in[9];
    const float* Wp2  = (const float*)d_in[10];
    const float* Wp3  = (const float*)d_in[11];
    const float* Wo   = (const float*)d_in[12];
    const float* bo   = (const float*)d_in[13];

    float* out = (float*)d_out;

    // ---- workspace (fp32, 10.9 MB — proven safe) ----
    float* qb  = (float*)d_ws;            // 1024x512
    float* kb  = qb  + 524288;
    float* vb  = kb  + 524288;            // v, later attn
    float* bb  = vb  + 524288;
    float* gb  = bb  + 524288;
    float* p1b = gb  + 524288;            // 1024x32
    float* p2b = p1b + 32768;
    float* p3b = p2b + 32768;

    ProjW pa;
    pa.W[0] = Wq;  pa.W[1] = Wk;  pa.W[2] = Wv;  pa.W[3] = Wb;
    pa.W[4] = Wg;  pa.W[5] = Wp1; pa.W[6] = Wp2; pa.W[7] = Wp3;
    pa.D[0] = qb;  pa.D[1] = kb;  pa.D[2] = vb;  pa.D[3] = bb;
    pa.D[4] = gb;  pa.D[5] = p1b; pa.D[6] = p2b; pa.D[7] = p3b;
    proj_kernel<<<dim3(16, 8, 8), 256, 0, stream>>>(X, pa);

    scan_kernel<<<512, 256, 0, stream>>>(qb, kb, vb, bb, gb, p1b, p2b, p3b,
                                         term, kv0, nm0, out);

    out_gemm_kernel<<<dim3(16, 8), 256, 0, stream>>>(vb, Wo, bo, out);
}

// Round 8
// 255.766 us; speedup vs baseline: 1.2524x; 1.0130x over previous
//
#include <hip/hip_runtime.h>

// GaLiTe attention layer, MI355X/gfx950 — all-fp32 (fp32 projections required:
// attn_den is a 256-term cancellation sum with ~1e6 error amplification at hot
// cells; ANY bf16-level perturbation fails — R2/R3. All scan inputs stay fp32.)
// Shapes: T=64 B=16 DIM=512 H=8 Dh=64 ETA=4 FD=256.
// d_out = fp32 [ output(64*16*512) | kv_last(16*8*256*64) | nm_last(16*8*256) ].
//
// R8 = R7 with ONE isolated change: SGEMM double-buffered LDS (1 barrier/tile
// instead of 2; prefetch loads overlap compute). Scan byte-identical to R7.

#define T_N   64
#define B_N   16
#define DIM_N 512
#define H_N   8
#define DH_N  64
#define ETA_N 4
#define FD_N  256

#define OUT_ELEMS   524288   // T*B*DIM
#define KV_ELEMS    2097152  // B*H*FD*Dh

__device__ __forceinline__ float sigmoidf_(float x) {
    return 1.0f / (1.0f + __expf(-x));
}

// ---------------------------------------------------------------------------
// fp32 SGEMM: C[m][n] = sum_k A[m][k]*W[n][k] (+bias), ldc=N, K=512.
// Block 256 thr; tile 64(m) x 64(n); BK=16; 4x4 microtile/thread.
// Double-buffered LDS: ONE __syncthreads per tile. Per iter i (buf=i&1):
//   barrier -> issue prefetch loads (tile i+1) -> compute from buf ->
//   ds_write tile i+1 into buf^1.
// Safety: barrier at top of iter i guarantees (a) iter i-1's writes to buf
// visible, (b) all waves' reads of buf^1 (iter i-1 compute) complete before
// iter i overwrites buf^1. LDS stride 68: conflict-free reads.
// ---------------------------------------------------------------------------
__device__ __forceinline__ void gemm64_db(const float* __restrict__ A,
                                          const float* __restrict__ W,
                                          const float* __restrict__ bias,
                                          float* __restrict__ C, int N) {
    const int nbase = blockIdx.y * 64;
    if (nbase >= N) return;                 // N=32 GEMMs: only y==0 active

    __shared__ float As[2][16][68];         // [buf][k][m], padded
    __shared__ float Bs[2][16][68];         // [buf][k][n], padded

    const int tid = threadIdx.x;
    const int mbase = blockIdx.x * 64;
    const int tx = tid & 15;                // n-quad
    const int ty = tid >> 4;                // m-quad
    const int sr = tid >> 2;                // staging row 0..63
    const int sk = (tid & 3) << 2;          // staging k 0,4,8,12
    const bool wok = (nbase + sr) < N;

    const float* Ap = A + (size_t)(mbase + sr) * 512 + sk;
    const float* Wp = W + (size_t)(nbase + sr) * 512 + sk;

    // stage tile 0 into buf 0 (no barrier needed before first loop barrier)
    float4 av = *(const float4*)Ap;
    float4 wv = wok ? *(const float4*)Wp : make_float4(0.f, 0.f, 0.f, 0.f);
    As[0][sk + 0][sr] = av.x; As[0][sk + 1][sr] = av.y;
    As[0][sk + 2][sr] = av.z; As[0][sk + 3][sr] = av.w;
    Bs[0][sk + 0][sr] = wv.x; Bs[0][sk + 1][sr] = wv.y;
    Bs[0][sk + 2][sr] = wv.z; Bs[0][sk + 3][sr] = wv.w;

    float acc[4][4];
    #pragma unroll
    for (int i = 0; i < 4; ++i)
        #pragma unroll
        for (int j = 0; j < 4; ++j) acc[i][j] = 0.f;

    for (int k0 = 0; k0 < 512; k0 += 16) {
        const int buf = (k0 >> 4) & 1;
        __syncthreads();
        const bool more = (k0 + 16) < 512;
        if (more) {                         // prefetch next tile (overlaps compute)
            av = *(const float4*)(Ap + k0 + 16);
            wv = wok ? *(const float4*)(Wp + k0 + 16) : make_float4(0.f, 0.f, 0.f, 0.f);
        }
        #pragma unroll
        for (int k = 0; k < 16; ++k) {
            float4 a  = *(const float4*)&As[buf][k][ty << 2];
            float4 bq = *(const float4*)&Bs[buf][k][tx << 2];
            float ar[4] = {a.x, a.y, a.z, a.w};
            float br[4] = {bq.x, bq.y, bq.z, bq.w};
            #pragma unroll
            for (int i = 0; i < 4; ++i)
                #pragma unroll
                for (int j = 0; j < 4; ++j)
                    acc[i][j] = fmaf(ar[i], br[j], acc[i][j]);
        }
        if (more) {                         // stage into the other buffer
            const int nb = buf ^ 1;
            As[nb][sk + 0][sr] = av.x; As[nb][sk + 1][sr] = av.y;
            As[nb][sk + 2][sr] = av.z; As[nb][sk + 3][sr] = av.w;
            Bs[nb][sk + 0][sr] = wv.x; Bs[nb][sk + 1][sr] = wv.y;
            Bs[nb][sk + 2][sr] = wv.z; Bs[nb][sk + 3][sr] = wv.w;
        }
    }

    #pragma unroll
    for (int i = 0; i < 4; ++i) {
        const int m = mbase + (ty << 2) + i;
        #pragma unroll
        for (int j = 0; j < 4; ++j) {
            const int n = nbase + (tx << 2) + j;
            if (n < N) {
                float v = acc[i][j];
                if (bias) v += bias[n];
                C[(size_t)m * N + n] = v;
            }
        }
    }
}

struct ProjW {
    const float* W[8];
    float*       D[8];
};

// z<5: N=512 (q,k,v,beta,gamma); z>=5: N=32 (p1,p2,p3). grid (16,8,8).
__global__ __launch_bounds__(256) void proj_kernel(const float* __restrict__ X, ProjW a) {
    const int z = blockIdx.z;
    const int N = (z < 5) ? 512 : 32;
    gemm64_db(X, a.W[z], nullptr, a.D[z], N);
}

// grid (16,8): out = attn @ Wo^T + bo
__global__ __launch_bounds__(256) void out_gemm_kernel(const float* __restrict__ A,
                                                       const float* __restrict__ W,
                                                       const float* __restrict__ bias,
                                                       float* __restrict__ C) {
    gemm64_db(A, W, bias, C, 512);
}

// ---------------------------------------------------------------------------
// Scan v3 (UNCHANGED from R7 — known-good): barrier-free, LDS-free.
// Grid 512: blk = bh*4 + s. Block 256 thr = 4 INDEPENDENT waves.
// Wave w covers d-cols dw = s*16 + w*4 .. +4.
// Lane l owns D in {4l..4l+4} x the wave's 4 d-cols: kv[4][4], nm[4].
//   D = e*64 + d_inner: e = l>>4, d_inner = 4*(l&15) + j.
// ---------------------------------------------------------------------------
__global__ __launch_bounds__(256) void scan_kernel(
    const float* __restrict__ qb,  const float* __restrict__ kb,
    float* vb /* v in, attn out */, const float* __restrict__ bb,
    const float* __restrict__ gb,  const float* __restrict__ p1b,
    const float* __restrict__ p2b, const float* __restrict__ p3b,
    const int* __restrict__ term,
    const float* __restrict__ kv0, const float* __restrict__ nm0,
    float* __restrict__ dout) {
    const int blk = blockIdx.x;       // 512 = 128 bh x 4 splits
    const int bh = blk >> 2;
    const int s  = blk & 3;
    const int b  = bh >> 3;
    const int h  = bh & 7;
    const int tid = threadIdx.x;
    const int w = tid >> 6;
    const int l = tid & 63;
    const int dw  = s * 16 + w * 4;   // wave's 4 d-cols
    const int D0  = l << 2;           // lane's first D
    const int eta = l >> 4;           // e = D0/64
    const int di0 = (l & 15) << 2;    // d_inner0 = D0 & 63

    // state: kv[j][c] = kv[D0+j][dw+c], nm[j] = nm[D0+j]
    float kv[4][4];
    float nm[4];
    {
        const float* kp = kv0 + ((size_t)bh * 256 + D0) * 64 + dw;
        #pragma unroll
        for (int j = 0; j < 4; ++j) {
            float4 r = *(const float4*)(kp + (size_t)j * 64);
            kv[j][0] = r.x; kv[j][1] = r.y; kv[j][2] = r.z; kv[j][3] = r.w;
        }
        float4 n4 = *(const float4*)(nm0 + (size_t)bh * 256 + D0);
        nm[0] = n4.x; nm[1] = n4.y; nm[2] = n4.z; nm[3] = n4.w;
    }

    // preload t=0
    float4 cq, ck, cg, cv, cb;
    float cp1, cp2, cp3, cmask;
    {
        const size_t base = (size_t)b * 512 + h * 64;
        const size_t pb = (size_t)b * 32 + h * 4;
        cq = *(const float4*)(qb + base + di0);
        ck = *(const float4*)(kb + base + di0);
        cg = *(const float4*)(gb + base + di0);
        cv = *(const float4*)(vb + base + dw);
        cb = *(const float4*)(bb + base + dw);
        cp1 = p1b[pb + eta]; cp2 = p2b[pb + eta]; cp3 = p3b[pb + eta];
        cmask = 1.0f - (float)term[b];
    }

    for (int t = 0; t < T_N; ++t) {
        const int row = t * B_N + b;
        const size_t base = (size_t)row * 512 + h * 64;

        // prefetch t+1
        float4 nq = {}, nk = {}, ng = {}, nv = {}, nb4 = {};
        float np1 = 0.f, np2 = 0.f, np3 = 0.f, nmask = 0.f;
        if (t + 1 < T_N) {
            const int r2 = row + B_N;
            const size_t b2 = (size_t)r2 * 512 + h * 64;
            const size_t pb2 = (size_t)r2 * 32 + h * 4;
            nq = *(const float4*)(qb + b2 + di0);
            nk = *(const float4*)(kb + b2 + di0);
            ng = *(const float4*)(gb + b2 + di0);
            nv = *(const float4*)(vb + b2 + dw);
            nb4 = *(const float4*)(bb + b2 + dw);
            np1 = p1b[pb2 + eta]; np2 = p2b[pb2 + eta]; np3 = p3b[pb2 + eta];
            nmask = 1.0f - (float)term[r2];
        }

        // gated_v for the wave's 4 d-cols (wave-uniform, redundant per lane)
        const float gv0 = cv.x * sigmoidf_(cb.x);
        const float gv1 = cv.y * sigmoidf_(cb.y);
        const float gv2 = cv.z * sigmoidf_(cb.z);
        const float gv3 = cv.w * sigmoidf_(cb.w);

        const float p1r = fmaxf(cp1, 0.f);
        const float p2r = fmaxf(cp2, 0.f);
        const float sp3 = sigmoidf_(cp3);

        const float qj[4] = {cq.x, cq.y, cq.z, cq.w};
        const float kj[4] = {ck.x, ck.y, ck.z, ck.w};
        const float gj[4] = {cg.x, cg.y, cg.z, cg.w};

        float denp = 0.f, n0 = 0.f, n1 = 0.f, n2 = 0.f, n3 = 0.f;
        #pragma unroll
        for (int j = 0; j < 4; ++j) {
            const float gf   = sp3 * sigmoidf_(gj[j]);
            const float phiq = p2r * qj[j];
            const float gk   = p1r * kj[j] * gf;
            const float disc = (1.0f - gf) * cmask;
            nm[j] = disc * nm[j] + gk;
            denp = fmaf(phiq, nm[j], denp);
            kv[j][0] = disc * kv[j][0] + gk * gv0; n0 = fmaf(phiq, kv[j][0], n0);
            kv[j][1] = disc * kv[j][1] + gk * gv1; n1 = fmaf(phiq, kv[j][1], n1);
            kv[j][2] = disc * kv[j][2] + gk * gv2; n2 = fmaf(phiq, kv[j][2], n2);
            kv[j][3] = disc * kv[j][3] + gk * gv3; n3 = fmaf(phiq, kv[j][3], n3);
        }

        // full-wave butterfly reductions (lane D-sets tile [0,256))
        #pragma unroll
        for (int ofs = 1; ofs < 64; ofs <<= 1) {
            n0   += __shfl_xor(n0, ofs);
            n1   += __shfl_xor(n1, ofs);
            n2   += __shfl_xor(n2, ofs);
            n3   += __shfl_xor(n3, ofs);
            denp += __shfl_xor(denp, ofs);
        }

        if (l < 4) {
            const float num = (l == 0) ? n0 : (l == 1) ? n1 : (l == 2) ? n2 : n3;
            vb[base + dw + l] = num / (denp + 1e-6f);   // attn -> v buffer
        }

        cq = nq; ck = nk; cg = ng; cv = nv; cb = nb4;
        cp1 = np1; cp2 = np2; cp3 = np3; cmask = nmask;
    }

    // final states -> d_out
    {
        float* kp = dout + OUT_ELEMS + ((size_t)bh * 256 + D0) * 64 + dw;
        #pragma unroll
        for (int j = 0; j < 4; ++j)
            *(float4*)(kp + (size_t)j * 64) = make_float4(kv[j][0], kv[j][1], kv[j][2], kv[j][3]);
        if (s == 0 && w == 0)
            *(float4*)(dout + OUT_ELEMS + KV_ELEMS + (size_t)bh * 256 + D0) =
                make_float4(nm[0], nm[1], nm[2], nm[3]);
    }
}

// ---------------------------------------------------------------------------
extern "C" void kernel_launch(void* const* d_in, const int* in_sizes, int n_in,
                              void* d_out, int out_size, void* d_ws, size_t ws_size,
                              hipStream_t stream) {
    (void)in_sizes; (void)n_in; (void)out_size; (void)ws_size;

    const float* X    = (const float*)d_in[0];
    const int*   term = (const int*)  d_in[1];
    const float* kv0  = (const float*)d_in[2];
    const float* nm0  = (const float*)d_in[3];
    const float* Wq   = (const float*)d_in[4];
    const float* Wk   = (const float*)d_in[5];
    const float* Wv   = (const float*)d_in[6];
    const float* Wb   = (const float*)d_in[7];
    const float* Wg   = (const float*)d_in[8];
    const float* Wp1  = (const float*)d_in[9];
    const float* Wp2  = (const float*)d_in[10];
    const float* Wp3  = (const float*)d_in[11];
    const float* Wo   = (const float*)d_in[12];
    const float* bo   = (const float*)d_in[13];

    float* out = (float*)d_out;

    // ---- workspace (fp32, 10.9 MB — proven safe) ----
    float* qb  = (float*)d_ws;            // 1024x512
    float* kb  = qb  + 524288;
    float* vb  = kb  + 524288;            // v, later attn
    float* bb  = vb  + 524288;
    float* gb  = bb  + 524288;
    float* p1b = gb  + 524288;            // 1024x32
    float* p2b = p1b + 32768;
    float* p3b = p2b + 32768;

    ProjW pa;
    pa.W[0] = Wq;  pa.W[1] = Wk;  pa.W[2] = Wv;  pa.W[3] = Wb;
    pa.W[4] = Wg;  pa.W[5] = Wp1; pa.W[6] = Wp2; pa.W[7] = Wp3;
    pa.D[0] = qb;  pa.D[1] = kb;  pa.D[2] = vb;  pa.D[3] = bb;
    pa.D[4] = gb;  pa.D[5] = p1b; pa.D[6] = p2b; pa.D[7] = p3b;
    proj_kernel<<<dim3(16, 8, 8), 256, 0, stream>>>(X, pa);

    scan_kernel<<<512, 256, 0, stream>>>(qb, kb, vb, bb, gb, p1b, p2b, p3b,
                                         term, kv0, nm0, out);

    out_gemm_kernel<<<dim3(16, 8), 256, 0, stream>>>(vb, Wo, bo, out);
}

// Round 9
// 238.237 us; speedup vs baseline: 1.3445x; 1.0736x over previous
//
#include <hip/hip_runtime.h>

// GaLiTe attention layer, MI355X/gfx950 — all-fp32 (fp32 projections required:
// attn_den is a 256-term cancellation sum; bf16 decorrelates it — R2/R3).
// Shapes: T=64 B=16 DIM=512 H=8 Dh=64 ETA=4 FD=256.
// d_out = fp32 [ output(64*16*512) | kv_last(16*8*256*64) | nm_last(16*8*256) ].
//
// R9: scan overhaul (GEMMs byte-identical to R8):
//  - gate_kernel precomputes disc/gk/phiq/gv (removes transcendentals + 5/9
//    loads from the t-loop). Requires ws 38.1 MB -> host guard on ws_size;
//    fallback = R7 scan (proven) if ws too small.
//  - scan4: d-split x8 -> 1024 blocks (4 waves/SIMD), 3 butterflies/t.

#define T_N   64
#define B_N   16
#define DIM_N 512
#define H_N   8
#define DH_N  64
#define ETA_N 4
#define FD_N  256

#define OUT_ELEMS   524288   // T*B*DIM
#define KV_ELEMS    2097152  // B*H*FD*Dh

__device__ __forceinline__ float sigmoidf_(float x) {
    return 1.0f / (1.0f + __expf(-x));
}

// ---------------------------------------------------------------------------
// fp32 SGEMM (unchanged from R8): 64x64 tile, BK=16, 4x4 micro, dbuf LDS.
// ---------------------------------------------------------------------------
__device__ __forceinline__ void gemm64_db(const float* __restrict__ A,
                                          const float* __restrict__ W,
                                          const float* __restrict__ bias,
                                          float* __restrict__ C, int N) {
    const int nbase = blockIdx.y * 64;
    if (nbase >= N) return;

    __shared__ float As[2][16][68];
    __shared__ float Bs[2][16][68];

    const int tid = threadIdx.x;
    const int mbase = blockIdx.x * 64;
    const int tx = tid & 15;
    const int ty = tid >> 4;
    const int sr = tid >> 2;
    const int sk = (tid & 3) << 2;
    const bool wok = (nbase + sr) < N;

    const float* Ap = A + (size_t)(mbase + sr) * 512 + sk;
    const float* Wp = W + (size_t)(nbase + sr) * 512 + sk;

    float4 av = *(const float4*)Ap;
    float4 wv = wok ? *(const float4*)Wp : make_float4(0.f, 0.f, 0.f, 0.f);
    As[0][sk + 0][sr] = av.x; As[0][sk + 1][sr] = av.y;
    As[0][sk + 2][sr] = av.z; As[0][sk + 3][sr] = av.w;
    Bs[0][sk + 0][sr] = wv.x; Bs[0][sk + 1][sr] = wv.y;
    Bs[0][sk + 2][sr] = wv.z; Bs[0][sk + 3][sr] = wv.w;

    float acc[4][4];
    #pragma unroll
    for (int i = 0; i < 4; ++i)
        #pragma unroll
        for (int j = 0; j < 4; ++j) acc[i][j] = 0.f;

    for (int k0 = 0; k0 < 512; k0 += 16) {
        const int buf = (k0 >> 4) & 1;
        __syncthreads();
        const bool more = (k0 + 16) < 512;
        if (more) {
            av = *(const float4*)(Ap + k0 + 16);
            wv = wok ? *(const float4*)(Wp + k0 + 16) : make_float4(0.f, 0.f, 0.f, 0.f);
        }
        #pragma unroll
        for (int k = 0; k < 16; ++k) {
            float4 a  = *(const float4*)&As[buf][k][ty << 2];
            float4 bq = *(const float4*)&Bs[buf][k][tx << 2];
            float ar[4] = {a.x, a.y, a.z, a.w};
            float br[4] = {bq.x, bq.y, bq.z, bq.w};
            #pragma unroll
            for (int i = 0; i < 4; ++i)
                #pragma unroll
                for (int j = 0; j < 4; ++j)
                    acc[i][j] = fmaf(ar[i], br[j], acc[i][j]);
        }
        if (more) {
            const int nb = buf ^ 1;
            As[nb][sk + 0][sr] = av.x; As[nb][sk + 1][sr] = av.y;
            As[nb][sk + 2][sr] = av.z; As[nb][sk + 3][sr] = av.w;
            Bs[nb][sk + 0][sr] = wv.x; Bs[nb][sk + 1][sr] = wv.y;
            Bs[nb][sk + 2][sr] = wv.z; Bs[nb][sk + 3][sr] = wv.w;
        }
    }

    #pragma unroll
    for (int i = 0; i < 4; ++i) {
        const int m = mbase + (ty << 2) + i;
        #pragma unroll
        for (int j = 0; j < 4; ++j) {
            const int n = nbase + (tx << 2) + j;
            if (n < N) {
                float v = acc[i][j];
                if (bias) v += bias[n];
                C[(size_t)m * N + n] = v;
            }
        }
    }
}

struct ProjW {
    const float* W[8];
    float*       D[8];
};

__global__ __launch_bounds__(256) void proj_kernel(const float* __restrict__ X, ProjW a) {
    const int z = blockIdx.z;
    const int N = (z < 5) ? 512 : 32;
    gemm64_db(X, a.W[z], nullptr, a.D[z], N);
}

__global__ __launch_bounds__(256) void out_gemm_kernel(const float* __restrict__ A,
                                                       const float* __restrict__ W,
                                                       const float* __restrict__ bias,
                                                       float* __restrict__ C) {
    gemm64_db(A, W, bias, C, 512);
}

// ---------------------------------------------------------------------------
// gate_kernel: precompute disc/gk/phiq (per t,b,h,D) and gv (per t,b,h,d).
// grid (1024 rows, 8 h), block 256 = D. Layout: [(row*8+h)*256 + D].
// ---------------------------------------------------------------------------
__global__ __launch_bounds__(256) void gate_kernel(
    const float* __restrict__ qb,  const float* __restrict__ kb,
    const float* __restrict__ vb,  const float* __restrict__ bb,
    const float* __restrict__ gb,  const float* __restrict__ p1b,
    const float* __restrict__ p2b, const float* __restrict__ p3b,
    const int* __restrict__ term,
    float* __restrict__ disc_g, float* __restrict__ gk_g,
    float* __restrict__ phiq_g, float* __restrict__ gv_g) {
    const int row = blockIdx.x;        // t*16 + b
    const int h = blockIdx.y;
    const int D = threadIdx.x;
    const int e = D >> 6, di = D & 63;
    const size_t base = (size_t)row * 512 + h * 64;
    const size_t pb = (size_t)row * 32 + h * 4;

    float q = qb[base + di], k = kb[base + di], g = gb[base + di];
    float p1 = p1b[pb + e], p2 = p2b[pb + e], p3 = p3b[pb + e];
    float mask = 1.0f - (float)term[row];
    float gf = sigmoidf_(p3) * sigmoidf_(g);

    const size_t o = ((size_t)row * 8 + h) * 256 + D;
    disc_g[o] = (1.0f - gf) * mask;
    gk_g[o]   = fmaxf(p1, 0.f) * k * gf;
    phiq_g[o] = fmaxf(p2, 0.f) * q;
    if (D < 64)
        gv_g[((size_t)row * 8 + h) * 64 + D] = vb[base + D] * sigmoidf_(bb[base + D]);
}

// ---------------------------------------------------------------------------
// scan4: d-split x8, precomputed gating. Grid 1024: blk = bh*8 + s.
// Block 256 thr = 4 independent waves; wave w: d-cols dw = s*8 + w*2 (2 cols).
// Lane l owns D = 4l..4l+4 (distinct across 64 lanes, tiles [0,256)):
//   kv[j][c] = kv[4l+j][dw+c], nm[j] = nm[4l+j] (nm redundant x8 blocks).
// Per t: 3 float4 gating loads (coalesced) + 1 float2 gv (broadcast);
// butterflies n0,n1,den over 64 lanes. No transcendentals, no barriers.
// attn -> vb is race-free: this kernel never reads vb.
// ---------------------------------------------------------------------------
__global__ __launch_bounds__(256) void scan4_kernel(
    const float* __restrict__ disc_g, const float* __restrict__ gk_g,
    const float* __restrict__ phiq_g, const float* __restrict__ gv_g,
    float* __restrict__ vb /* attn out */,
    const float* __restrict__ kv0, const float* __restrict__ nm0,
    float* __restrict__ dout) {
    const int blk = blockIdx.x;       // 1024 = 128 bh x 8 splits
    const int bh = blk >> 3;
    const int s  = blk & 7;
    const int b  = bh >> 3;
    const int h  = bh & 7;
    const int tid = threadIdx.x;
    const int w = tid >> 6;
    const int l = tid & 63;
    const int dw = s * 8 + w * 2;     // wave's 2 d-cols
    const int D0 = l << 2;

    float kv[4][2];
    float nm[4];
    const size_t kvoff = ((size_t)bh * 256 + D0) * 64 + dw;
    #pragma unroll
    for (int j = 0; j < 4; ++j) {
        float2 r = *(const float2*)(kv0 + kvoff + (size_t)j * 64);
        kv[j][0] = r.x; kv[j][1] = r.y;
    }
    {
        float4 n4 = *(const float4*)(nm0 + (size_t)bh * 256 + D0);
        nm[0] = n4.x; nm[1] = n4.y; nm[2] = n4.z; nm[3] = n4.w;
    }

    // preload t=0
    float4 cd, cgk, cph; float2 cgv;
    {
        const size_t go = ((size_t)b * 8 + h) * 256 + D0;
        const size_t gvo = ((size_t)b * 8 + h) * 64 + dw;
        cd  = *(const float4*)(disc_g + go);
        cgk = *(const float4*)(gk_g + go);
        cph = *(const float4*)(phiq_g + go);
        cgv = *(const float2*)(gv_g + gvo);
    }

    for (int t = 0; t < T_N; ++t) {
        const int row = t * B_N + b;
        const size_t base = (size_t)row * 512 + h * 64;

        // prefetch t+1
        float4 nd = {}, ngk = {}, nph = {}; float2 ngv = {};
        if (t + 1 < T_N) {
            const size_t go2 = ((size_t)(row + B_N) * 8 + h) * 256 + D0;
            const size_t gvo2 = ((size_t)(row + B_N) * 8 + h) * 64 + dw;
            nd  = *(const float4*)(disc_g + go2);
            ngk = *(const float4*)(gk_g + go2);
            nph = *(const float4*)(phiq_g + go2);
            ngv = *(const float2*)(gv_g + gvo2);
        }

        const float dj[4]  = {cd.x, cd.y, cd.z, cd.w};
        const float gkj[4] = {cgk.x, cgk.y, cgk.z, cgk.w};
        const float phj[4] = {cph.x, cph.y, cph.z, cph.w};

        float den = 0.f, n0 = 0.f, n1 = 0.f;
        #pragma unroll
        for (int j = 0; j < 4; ++j) {
            nm[j] = dj[j] * nm[j] + gkj[j];
            den = fmaf(phj[j], nm[j], den);
            kv[j][0] = dj[j] * kv[j][0] + gkj[j] * cgv.x; n0 = fmaf(phj[j], kv[j][0], n0);
            kv[j][1] = dj[j] * kv[j][1] + gkj[j] * cgv.y; n1 = fmaf(phj[j], kv[j][1], n1);
        }

        #pragma unroll
        for (int ofs = 1; ofs < 64; ofs <<= 1) {
            n0  += __shfl_xor(n0, ofs);
            n1  += __shfl_xor(n1, ofs);
            den += __shfl_xor(den, ofs);
        }

        if (l < 2) {
            const float num = (l == 0) ? n0 : n1;
            vb[base + dw + l] = num / (den + 1e-6f);
        }

        cd = nd; cgk = ngk; cph = nph; cgv = ngv;
    }

    // final states
    {
        float* kp = dout + OUT_ELEMS + kvoff;
        #pragma unroll
        for (int j = 0; j < 4; ++j)
            *(float2*)(kp + (size_t)j * 64) = make_float2(kv[j][0], kv[j][1]);
        if (s == 0 && w == 0)
            *(float4*)(dout + OUT_ELEMS + KV_ELEMS + (size_t)bh * 256 + D0) =
                make_float4(nm[0], nm[1], nm[2], nm[3]);
    }
}

// ---------------------------------------------------------------------------
// Fallback scan (R7, proven): used when ws_size < 38.1 MB.
// ---------------------------------------------------------------------------
__global__ __launch_bounds__(256) void scan_kernel(
    const float* __restrict__ qb,  const float* __restrict__ kb,
    float* vb, const float* __restrict__ bb,
    const float* __restrict__ gb,  const float* __restrict__ p1b,
    const float* __restrict__ p2b, const float* __restrict__ p3b,
    const int* __restrict__ term,
    const float* __restrict__ kv0, const float* __restrict__ nm0,
    float* __restrict__ dout) {
    const int blk = blockIdx.x;
    const int bh = blk >> 2;
    const int s  = blk & 3;
    const int b  = bh >> 3;
    const int h  = bh & 7;
    const int tid = threadIdx.x;
    const int w = tid >> 6;
    const int l = tid & 63;
    const int dw  = s * 16 + w * 4;
    const int D0  = l << 2;
    const int eta = l >> 4;
    const int di0 = (l & 15) << 2;

    float kv[4][4];
    float nm[4];
    const size_t kvoff = ((size_t)bh * 256 + D0) * 64 + dw;
    {
        const float* kp = kv0 + kvoff;
        #pragma unroll
        for (int j = 0; j < 4; ++j) {
            float4 r = *(const float4*)(kp + (size_t)j * 64);
            kv[j][0] = r.x; kv[j][1] = r.y; kv[j][2] = r.z; kv[j][3] = r.w;
        }
        float4 n4 = *(const float4*)(nm0 + (size_t)bh * 256 + D0);
        nm[0] = n4.x; nm[1] = n4.y; nm[2] = n4.z; nm[3] = n4.w;
    }

    float4 cq, ck, cg, cv, cb;
    float cp1, cp2, cp3, cmask;
    {
        const size_t base = (size_t)b * 512 + h * 64;
        const size_t pb = (size_t)b * 32 + h * 4;
        cq = *(const float4*)(qb + base + di0);
        ck = *(const float4*)(kb + base + di0);
        cg = *(const float4*)(gb + base + di0);
        cv = *(const float4*)(vb + base + dw);
        cb = *(const float4*)(bb + base + dw);
        cp1 = p1b[pb + eta]; cp2 = p2b[pb + eta]; cp3 = p3b[pb + eta];
        cmask = 1.0f - (float)term[b];
    }

    for (int t = 0; t < T_N; ++t) {
        const int row = t * B_N + b;
        const size_t base = (size_t)row * 512 + h * 64;

        float4 nq = {}, nk = {}, ng = {}, nv = {}, nb4 = {};
        float np1 = 0.f, np2 = 0.f, np3 = 0.f, nmask = 0.f;
        if (t + 1 < T_N) {
            const int r2 = row + B_N;
            const size_t b2 = (size_t)r2 * 512 + h * 64;
            const size_t pb2 = (size_t)r2 * 32 + h * 4;
            nq = *(const float4*)(qb + b2 + di0);
            nk = *(const float4*)(kb + b2 + di0);
            ng = *(const float4*)(gb + b2 + di0);
            nv = *(const float4*)(vb + b2 + dw);
            nb4 = *(const float4*)(bb + b2 + dw);
            np1 = p1b[pb2 + eta]; np2 = p2b[pb2 + eta]; np3 = p3b[pb2 + eta];
            nmask = 1.0f - (float)term[r2];
        }

        const float gv0 = cv.x * sigmoidf_(cb.x);
        const float gv1 = cv.y * sigmoidf_(cb.y);
        const float gv2 = cv.z * sigmoidf_(cb.z);
        const float gv3 = cv.w * sigmoidf_(cb.w);

        const float p1r = fmaxf(cp1, 0.f);
        const float p2r = fmaxf(cp2, 0.f);
        const float sp3 = sigmoidf_(cp3);

        const float qj[4] = {cq.x, cq.y, cq.z, cq.w};
        const float kj[4] = {ck.x, ck.y, ck.z, ck.w};
        const float gj[4] = {cg.x, cg.y, cg.z, cg.w};

        float denp = 0.f, n0 = 0.f, n1 = 0.f, n2 = 0.f, n3 = 0.f;
        #pragma unroll
        for (int j = 0; j < 4; ++j) {
            const float gf   = sp3 * sigmoidf_(gj[j]);
            const float phiq = p2r * qj[j];
            const float gk   = p1r * kj[j] * gf;
            const float disc = (1.0f - gf) * cmask;
            nm[j] = disc * nm[j] + gk;
            denp = fmaf(phiq, nm[j], denp);
            kv[j][0] = disc * kv[j][0] + gk * gv0; n0 = fmaf(phiq, kv[j][0], n0);
            kv[j][1] = disc * kv[j][1] + gk * gv1; n1 = fmaf(phiq, kv[j][1], n1);
            kv[j][2] = disc * kv[j][2] + gk * gv2; n2 = fmaf(phiq, kv[j][2], n2);
            kv[j][3] = disc * kv[j][3] + gk * gv3; n3 = fmaf(phiq, kv[j][3], n3);
        }

        #pragma unroll
        for (int ofs = 1; ofs < 64; ofs <<= 1) {
            n0   += __shfl_xor(n0, ofs);
            n1   += __shfl_xor(n1, ofs);
            n2   += __shfl_xor(n2, ofs);
            n3   += __shfl_xor(n3, ofs);
            denp += __shfl_xor(denp, ofs);
        }

        if (l < 4) {
            const float num = (l == 0) ? n0 : (l == 1) ? n1 : (l == 2) ? n2 : n3;
            vb[base + dw + l] = num / (denp + 1e-6f);
        }

        cq = nq; ck = nk; cg = ng; cv = nv; cb = nb4;
        cp1 = np1; cp2 = np2; cp3 = np3; cmask = nmask;
    }

    {
        float* kp = dout + OUT_ELEMS + kvoff;
        #pragma unroll
        for (int j = 0; j < 4; ++j)
            *(float4*)(kp + (size_t)j * 64) = make_float4(kv[j][0], kv[j][1], kv[j][2], kv[j][3]);
        if (s == 0 && w == 0)
            *(float4*)(dout + OUT_ELEMS + KV_ELEMS + (size_t)bh * 256 + D0) =
                make_float4(nm[0], nm[1], nm[2], nm[3]);
    }
}

// ---------------------------------------------------------------------------
extern "C" void kernel_launch(void* const* d_in, const int* in_sizes, int n_in,
                              void* d_out, int out_size, void* d_ws, size_t ws_size,
                              hipStream_t stream) {
    (void)in_sizes; (void)n_in; (void)out_size;

    const float* X    = (const float*)d_in[0];
    const int*   term = (const int*)  d_in[1];
    const float* kv0  = (const float*)d_in[2];
    const float* nm0  = (const float*)d_in[3];
    const float* Wq   = (const float*)d_in[4];
    const float* Wk   = (const float*)d_in[5];
    const float* Wv   = (const float*)d_in[6];
    const float* Wb   = (const float*)d_in[7];
    const float* Wg   = (const float*)d_in[8];
    const float* Wp1  = (const float*)d_in[9];
    const float* Wp2  = (const float*)d_in[10];
    const float* Wp3  = (const float*)d_in[11];
    const float* Wo   = (const float*)d_in[12];
    const float* bo   = (const float*)d_in[13];

    float* out = (float*)d_out;

    // ---- base workspace (10.88 MB, proven) ----
    float* qb  = (float*)d_ws;            // 1024x512
    float* kb  = qb  + 524288;
    float* vb  = kb  + 524288;            // v, later attn
    float* bb  = vb  + 524288;
    float* gb  = bb  + 524288;
    float* p1b = gb  + 524288;            // 1024x32
    float* p2b = p1b + 32768;
    float* p3b = p2b + 32768;
    float* extra = p3b + 32768;           // +2,719,744 floats from base

    // ---- big path extras: disc/gk/phiq (3 x 2M) + gv (0.5M) = 26 MB ----
    float* disc_g = extra;
    float* gk_g   = disc_g + 2097152;
    float* phiq_g = gk_g   + 2097152;
    float* gv_g   = phiq_g + 2097152;
    const size_t need_bytes = (size_t)(2719744 + 3 * 2097152 + 524288) * 4;  // 38.1 MB
    const bool big = ws_size >= need_bytes;

    ProjW pa;
    pa.W[0] = Wq;  pa.W[1] = Wk;  pa.W[2] = Wv;  pa.W[3] = Wb;
    pa.W[4] = Wg;  pa.W[5] = Wp1; pa.W[6] = Wp2; pa.W[7] = Wp3;
    pa.D[0] = qb;  pa.D[1] = kb;  pa.D[2] = vb;  pa.D[3] = bb;
    pa.D[4] = gb;  pa.D[5] = p1b; pa.D[6] = p2b; pa.D[7] = p3b;
    proj_kernel<<<dim3(16, 8, 8), 256, 0, stream>>>(X, pa);

    if (big) {
        gate_kernel<<<dim3(1024, 8), 256, 0, stream>>>(qb, kb, vb, bb, gb,
                                                       p1b, p2b, p3b, term,
                                                       disc_g, gk_g, phiq_g, gv_g);
        scan4_kernel<<<1024, 256, 0, stream>>>(disc_g, gk_g, phiq_g, gv_g,
                                               vb, kv0, nm0, out);
    } else {
        scan_kernel<<<512, 256, 0, stream>>>(qb, kb, vb, bb, gb, p1b, p2b, p3b,
                                             term, kv0, nm0, out);
    }

    out_gemm_kernel<<<dim3(16, 8), 256, 0, stream>>>(vb, Wo, bo, out);
}